// Round 7
// baseline (101.457 us; speedup 1.0000x reference)
//
#include <hip/hip_runtime.h>

// Involution: x(2,64,64,256) f32
//   t    = relu(BN(x @ w1 + b1))            (8192 x 64)
//   kern = t @ w2 + b2                      (8192 x 784), 784 = 49 taps * 16 groups
//   out[p][c] = sum_kk kern[p][kk*16 + c%16] * x_zpad[p + tap(kk)][c]
// d_out = [ out : 2097152 floats | kern : 6422528 floats ]
//
// Round-7: 8-px tiles, 1024 blocks (4/CU, 16 waves/CU = 2x latency hiding vs
// round 6). Weights moved to d_ws (removes the out-region race). Same fused
// structure: stage x -> MFMA t -> MFMA kern (global + LDS) -> apply from LDS.

typedef __attribute__((ext_vector_type(8))) short short8;   // 8 bf16 = 4 VGPR
typedef __attribute__((ext_vector_type(4))) float f32x4;

#define OUT_ELEMS 2097152
#define W2S_OFF 0                       // ushort[49*2*64*8]  (100352 B) frag order
#define W1S_OFF 131072                  // ushort[4*8*64*8]   (32768 B)  frag order
#define BNS_OFF (131072 + 32768)        // float[64] scale
#define BNH_OFF (BNS_OFF + 256)         // float[64] shift

static __device__ __forceinline__ ushort f2bf(float f) {
    union { float f; unsigned u; } v; v.f = f;
    return (ushort)((v.u + 0x7FFFu + ((v.u >> 16) & 1u)) >> 16);   // RNE
}

// ---------------------------------------------------------------------------
// prep: weights -> bf16 in MFMA B-frag layout (into d_ws).
//   w2s[((kg*2+ks)*64+lane)*8+e] = bf16(w2[k][n]), n=kg*16+(lane&15),
//                                  k=ks*32+(lane>>4)*8+e
//   w1s[((nt*8+ks)*64+lane)*8+e] = bf16(w1[k][n]), n=nt*16+(lane&15), same k
//   bns[d]=gamma*rsqrt(var+eps), bnh[d]=beta+(b1-mu)*bns
// ---------------------------------------------------------------------------
__global__ __launch_bounds__(256)
void prep(const float* __restrict__ w1, const float* __restrict__ w2,
          const float* __restrict__ b1, const float* __restrict__ gamma_,
          const float* __restrict__ beta_, const float* __restrict__ mu_,
          const float* __restrict__ var_, char* __restrict__ base)
{
    const int g = blockIdx.x * 256 + threadIdx.x;
    ushort* w2s = (ushort*)(base + W2S_OFF);
    ushort* w1s = (ushort*)(base + W1S_OFF);
    float*  bns = (float*)(base + BNS_OFF);
    float*  bnh = (float*)(base + BNH_OFF);
    if (g < 50176) {
        const int e = g & 7, lane = (g >> 3) & 63, kgks = g >> 9;
        const int kg = kgks >> 1, ks = kgks & 1;
        const int n = kg * 16 + (lane & 15);
        const int k = ks * 32 + ((lane >> 4) << 3) + e;
        w2s[g] = f2bf(w2[k * 784 + n]);
    } else if (g < 66560) {
        const int e2 = g - 50176;
        const int e = e2 & 7, lane = (e2 >> 3) & 63, ntks = e2 >> 9;
        const int nt = ntks >> 3, ks = ntks & 7;
        const int n = nt * 16 + (lane & 15);
        const int k = ks * 32 + ((lane >> 4) << 3) + e;
        w1s[e2] = f2bf(w1[k * 64 + n]);
    } else if (g < 66624) {
        const int d = g - 66560;
        const float s = gamma_[d] * rsqrtf(var_[d] + 1e-3f);
        bns[d] = s;
        bnh[d] = beta_[d] + (b1[d] - mu_[d]) * s;
    }
}

// ---------------------------------------------------------------------------
// invol_fused: grid 1024 (XCD-swizzled: xcd owns px [xcd*1024,+1024)), 256 thr.
// Block = 8-px row-segment (w 8-aligned). Phases:
//   1. stage x(8x256) -> bf16 xb (XOR-swz)
//   2. t = BN/ReLU(x @ w1s): wave wv -> n-block wv; A rows mrow&7 (dup, M=16
//      half-used); store rows<8 (qlane<2)
//   3. hoist phase-4 A-frags from tb; barrier; kl overlays xb/tb
//   4. kern = t @ w2s + b2: wave does kg = wv,wv+4,..; C rows<8 -> global+kl
//   5. apply: 2 px/wave, lane owns 4 ch; x f32 from global (L1/L2-hot),
//      kern from kl (conflict-free b128 broadcast).
// ---------------------------------------------------------------------------
#define FMA4(A, K, X) \
    A.x = fmaf(K.x, X.x, A.x); A.y = fmaf(K.y, X.y, A.y); \
    A.z = fmaf(K.z, X.z, A.z); A.w = fmaf(K.w, X.w, A.w);

__global__ __launch_bounds__(256)
void invol_fused(const float* __restrict__ x, const char* __restrict__ base,
                 const float* __restrict__ b2, float* __restrict__ kern_out,
                 float* __restrict__ out)
{
    __shared__ __align__(16) union {
        struct { ushort xb[2048]; ushort tb[1024]; } s;  // 4 KB + 2 KB (ph 1-3)
        float kl[6272];                                   // 8*784 f32 (ph 4-5)
    } u;

    const ushort* w2s = (const ushort*)(base + W2S_OFF);
    const ushort* w1s = (const ushort*)(base + W1S_OFF);
    const float*  bns = (const float*)(base + BNS_OFF);
    const float*  bnh = (const float*)(base + BNH_OFF);

    const int tid  = threadIdx.x;
    const int lane = tid & 63;
    const int wv   = tid >> 6;            // 0..3
    const int bid  = blockIdx.x;          // 0..1023
    const int pb   = ((bid & 7) << 10) + ((bid >> 3) << 3);   // 8-px base
    const int b  = pb >> 12;
    const int h  = (pb >> 6) & 63;
    const int w0 = pb & 63;               // multiple of 8

    // ---- phase 1: stage x tile (8px x 256c) -> bf16 LDS, swizzled ----
#pragma unroll
    for (int i = 0; i < 2; ++i) {
        const int f4 = tid + 256 * i;     // 0..511
        const int px = f4 >> 6;           // 0..7
        const int c0 = (f4 & 63) * 4;
        const float4 v = *(const float4*)(x + (size_t)(pb + px) * 256 + c0);
        ushort4 hh;
        hh.x = f2bf(v.x); hh.y = f2bf(v.y); hh.z = f2bf(v.z); hh.w = f2bf(v.w);
        const int byte = ((px << 9) + (c0 << 1)) ^ ((px & 7) << 4);
        *(ushort4*)((char*)u.s.xb + byte) = hh;
    }
    __syncthreads();

    const int qlane = lane >> 4;          // 0..3
    const int mrow  = lane & 15;
    const int apx   = mrow & 7;           // A row: rows 8-15 duplicate 0-7
    const int aswz  = (apx & 7) << 4;

    // ---- phase 2: t = BN/ReLU(x @ w1s); wave wv -> 8px x 16n (n-block wv) ----
    f32x4 acc = {0.f, 0.f, 0.f, 0.f};
#pragma unroll
    for (int ks = 0; ks < 8; ++ks) {
        const short8 a = *(const short8*)((const char*)u.s.xb +
                          (((apx << 9) + ((ks * 32 + qlane * 8) << 1)) ^ aswz));
        const short8 bv = *(const short8*)(w1s + ((wv * 8 + ks) * 64 + lane) * 8);
        acc = __builtin_amdgcn_mfma_f32_16x16x32_bf16(a, bv, acc, 0, 0, 0);
    }
    if (qlane < 2) {   // C/D: col = lane&15, row = qlane*4 + r ; keep rows 0-7
        const int col = wv * 16 + mrow;
        const float s = bns[col], sh = bnh[col];
#pragma unroll
        for (int r = 0; r < 4; ++r) {
            const int row = qlane * 4 + r;
            const float tv = fmaxf(fmaf(acc[r], s, sh), 0.f);
            const int byte = ((row << 7) + (col << 1)) ^ ((row & 7) << 4);
            *(ushort*)((char*)u.s.tb + byte) = f2bf(tv);
        }
    }
    __syncthreads();

    // ---- phase 3: hoist phase-4 A-frags (rows mrow&7); then xb/tb dead ----
    const short8 a0 = *(const short8*)((const char*)u.s.tb +
                        (((apx << 7) + (qlane << 4)) ^ aswz));
    const short8 a1 = *(const short8*)((const char*)u.s.tb +
                        (((apx << 7) + 64 + (qlane << 4)) ^ aswz));
    __syncthreads();                      // all tb reads done -> kl may overwrite

    // ---- phase 4: kern = t @ w2s + b2 -> global + kl (rows 0-7) ----
    for (int kg = wv; kg < 49; kg += 4) {
        const short8 bv0 = *(const short8*)(w2s + (size_t)((kg * 2 + 0) * 64 + lane) * 8);
        const short8 bv1 = *(const short8*)(w2s + (size_t)((kg * 2 + 1) * 64 + lane) * 8);
        f32x4 c = {0.f, 0.f, 0.f, 0.f};
        c = __builtin_amdgcn_mfma_f32_16x16x32_bf16(a0, bv0, c, 0, 0, 0);
        c = __builtin_amdgcn_mfma_f32_16x16x32_bf16(a1, bv1, c, 0, 0, 0);
        if (qlane < 2) {
            const int n = kg * 16 + mrow;
            const float bias = b2[n];
#pragma unroll
            for (int r = 0; r < 4; ++r) {
                const int row = qlane * 4 + r;
                const float val = c[r] + bias;
                kern_out[(size_t)(pb + row) * 784 + n] = val;
                u.kl[row * 784 + n] = val;
            }
        }
    }
    __syncthreads();

    // ---- phase 5: apply; wave wv owns px wv*2, wv*2+1; lane owns 4 ch ----
    const int c0  = lane * 4;
    const int g0  = c0 & 15;
    const int w0w = w0 + wv * 2;
    const float* xbase = x + ((size_t)b << 20);

    float msk[8]; int colc[8];
#pragma unroll
    for (int j = 0; j < 8; ++j) {
        const int cw = w0w + j - 3;
        msk[j]  = ((unsigned)cw < 64u) ? 1.0f : 0.0f;
        colc[j] = (min(max(cw, 0), 63) << 8) + c0;
    }

    float4 acc4[2];
    acc4[0] = make_float4(0.f, 0.f, 0.f, 0.f);
    acc4[1] = make_float4(0.f, 0.f, 0.f, 0.f);

#pragma unroll
    for (int kh = 0; kh < 7; ++kh) {
        const int hh = h + kh - 3;
        if ((unsigned)hh < 64u) {                     // block-uniform
            const float* xr = xbase + ((size_t)hh << 14);
            float4 xv[8];
#pragma unroll
            for (int j = 0; j < 8; ++j) {
                xv[j] = *(const float4*)(xr + colc[j]);
                xv[j].x *= msk[j]; xv[j].y *= msk[j];
                xv[j].z *= msk[j]; xv[j].w *= msk[j];
            }
#pragma unroll
            for (int p = 0; p < 2; ++p) {
                const float* kr = u.kl + (wv * 2 + p) * 784 + kh * 112 + g0;
#pragma unroll
                for (int kw = 0; kw < 7; ++kw) {
                    const float4 kv = *(const float4*)(kr + kw * 16);
                    FMA4(acc4[p], kv, xv[p + kw]);
                }
            }
        }
    }
#pragma unroll
    for (int p = 0; p < 2; ++p)
        *(float4*)(out + (size_t)(pb + wv * 2 + p) * 256 + c0) = acc4[p];
}

extern "C" void kernel_launch(void* const* d_in, const int* in_sizes, int n_in,
                              void* d_out, int out_size, void* d_ws, size_t ws_size,
                              hipStream_t stream)
{
    const float* x      = (const float*)d_in[0];
    const float* w1     = (const float*)d_in[1];
    const float* b1     = (const float*)d_in[2];
    const float* gamma_ = (const float*)d_in[3];
    const float* beta_  = (const float*)d_in[4];
    const float* mu_    = (const float*)d_in[5];
    const float* var_   = (const float*)d_in[6];
    const float* w2     = (const float*)d_in[7];
    const float* b2     = (const float*)d_in[8];

    float* out  = (float*)d_out;
    float* kern = out + OUT_ELEMS;
    char*  base = (char*)d_ws;     // prepped weights live in scratch (d_ws);
                                   // re-poisoned before every launch, prep
                                   // rewrites them every launch.

    prep<<<261, 256, 0, stream>>>(w1, w2, b1, gamma_, beta_, mu_, var_, base);
    invol_fused<<<1024, 256, 0, stream>>>(x, base, b2, kern, out);
}

// Round 9
// 97.223 us; speedup vs baseline: 1.0436x; 1.0436x over previous
//
#include <hip/hip_runtime.h>

// Involution: x(2,64,64,256) f32
//   t    = relu(BN(x @ w1 + b1))            (8192 x 64)
//   kern = t @ w2 + b2                      (8192 x 784), 784 = 49 taps * 16 groups
//   out[p][c] = sum_kk kern[p][kk*16 + c%16] * x_zpad[p + tap(kk)][c]
// d_out = [ out : 2097152 floats | kern : 6422528 floats ]
//
// Round-9: r6 structure (16-px tiles / 512 blocks / lane owns 4 consecutive
// channels — CORRECT, covers all 256 ch) + latency fixes:
//   - phase 4: 2-deep register prefetch of w2s B-fragments
//   - phase 5: branchless kh (clamped row + row-mask folded into xv mask)
//     so all 70 x loads are straight-line and pipeline across kh rows
//   - tb split from the kl union (one fewer barrier, race-checked)

typedef __attribute__((ext_vector_type(8))) short short8;   // 8 bf16 = 4 VGPR
typedef __attribute__((ext_vector_type(4))) float f32x4;

#define OUT_ELEMS 2097152
#define W2S_OFF 0                       // ushort[49*2*64*8]  (100352 B) frag order
#define W1S_OFF 131072                  // ushort[4*8*64*8]   (32768 B)  frag order
#define BNS_OFF (131072 + 32768)        // float[64] scale
#define BNH_OFF (BNS_OFF + 256)         // float[64] shift

static __device__ __forceinline__ ushort f2bf(float f) {
    union { float f; unsigned u; } v; v.f = f;
    return (ushort)((v.u + 0x7FFFu + ((v.u >> 16) & 1u)) >> 16);   // RNE
}

// ---------------------------------------------------------------------------
// prep: weights -> bf16 in MFMA B-frag layout (into d_ws).
//   w2s[((kg*2+ks)*64+lane)*8+e] = bf16(w2[k][n]), n=kg*16+(lane&15),
//                                  k=ks*32+(lane>>4)*8+e
//   w1s[((nt*8+ks)*64+lane)*8+e] = bf16(w1[k][n]), n=nt*16+(lane&15), same k
//   bns[d]=gamma*rsqrt(var+eps), bnh[d]=beta+(b1-mu)*bns
// ---------------------------------------------------------------------------
__global__ __launch_bounds__(256)
void prep(const float* __restrict__ w1, const float* __restrict__ w2,
          const float* __restrict__ b1, const float* __restrict__ gamma_,
          const float* __restrict__ beta_, const float* __restrict__ mu_,
          const float* __restrict__ var_, char* __restrict__ base)
{
    const int g = blockIdx.x * 256 + threadIdx.x;
    ushort* w2s = (ushort*)(base + W2S_OFF);
    ushort* w1s = (ushort*)(base + W1S_OFF);
    float*  bns = (float*)(base + BNS_OFF);
    float*  bnh = (float*)(base + BNH_OFF);
    if (g < 50176) {
        const int e = g & 7, lane = (g >> 3) & 63, kgks = g >> 9;
        const int kg = kgks >> 1, ks = kgks & 1;
        const int n = kg * 16 + (lane & 15);
        const int k = ks * 32 + ((lane >> 4) << 3) + e;
        w2s[g] = f2bf(w2[k * 784 + n]);
    } else if (g < 66560) {
        const int e2 = g - 50176;
        const int e = e2 & 7, lane = (e2 >> 3) & 63, ntks = e2 >> 9;
        const int nt = ntks >> 3, ks = ntks & 7;
        const int n = nt * 16 + (lane & 15);
        const int k = ks * 32 + ((lane >> 4) << 3) + e;
        w1s[e2] = f2bf(w1[k * 64 + n]);
    } else if (g < 66624) {
        const int d = g - 66560;
        const float s = gamma_[d] * rsqrtf(var_[d] + 1e-3f);
        bns[d] = s;
        bnh[d] = beta_[d] + (b1[d] - mu_[d]) * s;
    }
}

// ---------------------------------------------------------------------------
// invol_fused: grid 512 (XCD-swizzled: xcd owns px [xcd*1024,+1024)), 256 thr.
// Block = 16-px row-segment. Phases (3 barriers):
//   1. stage x(16x256) -> bf16 xb (XOR-swz)                        [barrier]
//   2. t = BN/ReLU(x @ w1s): wave wv -> n-block wv -> tb           [barrier]
//   3. hoist phase-4 A-frags from tb (tb separate from kl union)
//   4. kern = t @ w2s + b2, 2-deep w2s prefetch -> global + kl     [barrier]
//   5. apply (branchless): wave wv owns px wv*4..+3, lane owns 4 consecutive
//      channels; 10 masked float4 x loads per kh serve 4 px x 7 taps; kern
//      from kl (4 distinct b128 addrs -> banks 0..15, conflict-free).
// ---------------------------------------------------------------------------
#define FMA4(A, K, X) \
    A.x = fmaf(K.x, X.x, A.x); A.y = fmaf(K.y, X.y, A.y); \
    A.z = fmaf(K.z, X.z, A.z); A.w = fmaf(K.w, X.w, A.w);

__global__ __launch_bounds__(256)
void invol_fused(const float* __restrict__ x, const char* __restrict__ base,
                 const float* __restrict__ b2, float* __restrict__ kern_out,
                 float* __restrict__ out)
{
    __shared__ __align__(16) union {
        ushort xb[4096];    // 8 KB (phases 1-2)
        float  kl[12544];   // 16*784 f32 = 50176 B (phases 4-5)
    } u;
    __shared__ __align__(16) ushort tb[1024];   // 2 KB, phases 2-4

    const ushort* w2s = (const ushort*)(base + W2S_OFF);
    const ushort* w1s = (const ushort*)(base + W1S_OFF);
    const float*  bns = (const float*)(base + BNS_OFF);
    const float*  bnh = (const float*)(base + BNH_OFF);

    const int tid  = threadIdx.x;
    const int lane = tid & 63;
    const int wv   = tid >> 6;            // 0..3
    const int bid  = blockIdx.x;          // 0..511
    const int pb   = ((bid & 7) << 10) + ((bid >> 3) << 4);   // 16-px base
    const int b  = pb >> 12;
    const int h  = (pb >> 6) & 63;
    const int w0 = pb & 63;               // multiple of 16

    // ---- phase 1: stage x tile (16px x 256c) -> bf16 LDS, swizzled ----
#pragma unroll
    for (int i = 0; i < 4; ++i) {
        const int f4 = tid + 256 * i;     // 0..1023
        const int px = f4 >> 6;           // 0..15
        const int c0 = (f4 & 63) * 4;
        const float4 v = *(const float4*)(x + (size_t)(pb + px) * 256 + c0);
        ushort4 hh;
        hh.x = f2bf(v.x); hh.y = f2bf(v.y); hh.z = f2bf(v.z); hh.w = f2bf(v.w);
        const int byte = ((px << 9) + (c0 << 1)) ^ ((px & 7) << 4);
        *(ushort4*)((char*)u.xb + byte) = hh;
    }
    __syncthreads();

    const int qlane = lane >> 4;          // 0..3
    const int mrow  = lane & 15;
    const int aswz  = (mrow & 7) << 4;

    // ---- phase 2: t = BN/ReLU(x @ w1s); wave wv -> 16px x 16n (n-block wv) ----
    f32x4 acc = {0.f, 0.f, 0.f, 0.f};
#pragma unroll
    for (int ks = 0; ks < 8; ++ks) {
        const short8 a = *(const short8*)((const char*)u.xb +
                          (((mrow << 9) + ((ks * 32 + qlane * 8) << 1)) ^ aswz));
        const short8 bv = *(const short8*)(w1s + ((wv * 8 + ks) * 64 + lane) * 8);
        acc = __builtin_amdgcn_mfma_f32_16x16x32_bf16(a, bv, acc, 0, 0, 0);
    }
    {   // C/D: col = lane&15, row = qlane*4 + r
        const int col = wv * 16 + mrow;
        const float s = bns[col], sh = bnh[col];
#pragma unroll
        for (int r = 0; r < 4; ++r) {
            const int row = qlane * 4 + r;
            const float tv = fmaxf(fmaf(acc[r], s, sh), 0.f);
            const int byte = ((row << 7) + (col << 1)) ^ ((row & 7) << 4);
            *(ushort*)((char*)tb + byte) = f2bf(tv);
        }
    }
    __syncthreads();   // tb complete; all xb reads done -> kl may overwrite xb

    // ---- phase 3: hoist phase-4 A-frags from tb (no barrier needed) ----
    const short8 a0 = *(const short8*)((const char*)tb +
                        (((mrow << 7) + (qlane << 4)) ^ aswz));
    const short8 a1 = *(const short8*)((const char*)tb +
                        (((mrow << 7) + 64 + (qlane << 4)) ^ aswz));

    // ---- phase 4: kern = t @ w2s + b2 -> global + kl; 2-deep prefetch ----
    short8 wa0, wa1, wb0, wb1;
    {
        wa0 = *(const short8*)(w2s + (size_t)((wv * 2 + 0) * 64 + lane) * 8);
        wa1 = *(const short8*)(w2s + (size_t)((wv * 2 + 1) * 64 + lane) * 8);
        const int k1 = (wv + 4 < 49) ? wv + 4 : wv;
        wb0 = *(const short8*)(w2s + (size_t)((k1 * 2 + 0) * 64 + lane) * 8);
        wb1 = *(const short8*)(w2s + (size_t)((k1 * 2 + 1) * 64 + lane) * 8);
    }
#pragma unroll 2
    for (int kg = wv; kg < 49; kg += 4) {
        const short8 ua = wa0, ub = wa1;
        wa0 = wb0; wa1 = wb1;
        const int kn = (kg + 8 < 49) ? kg + 8 : wv;    // clamped (branchless)
        wb0 = *(const short8*)(w2s + (size_t)((kn * 2 + 0) * 64 + lane) * 8);
        wb1 = *(const short8*)(w2s + (size_t)((kn * 2 + 1) * 64 + lane) * 8);

        f32x4 c = {0.f, 0.f, 0.f, 0.f};
        c = __builtin_amdgcn_mfma_f32_16x16x32_bf16(a0, ua, c, 0, 0, 0);
        c = __builtin_amdgcn_mfma_f32_16x16x32_bf16(a1, ub, c, 0, 0, 0);
        const int n = kg * 16 + mrow;
        const float bias = b2[n];
#pragma unroll
        for (int r = 0; r < 4; ++r) {
            const int row = qlane * 4 + r;
            const float val = c[r] + bias;
            kern_out[(size_t)(pb + row) * 784 + n] = val;
            u.kl[row * 784 + n] = val;
        }
    }
    __syncthreads();

    // ---- phase 5: apply (branchless); wave wv owns px wv*4..+3 ----
    const int c0  = lane * 4;             // 4 consecutive channels
    const int g0  = c0 & 15;
    const int w0w = w0 + wv * 4;
    const float* xbase = x + ((size_t)b << 20);

    float msk[10]; int colc[10];
#pragma unroll
    for (int j = 0; j < 10; ++j) {
        const int cw = w0w + j - 3;
        msk[j]  = ((unsigned)cw < 64u) ? 1.0f : 0.0f;
        colc[j] = (min(max(cw, 0), 63) << 8) + c0;
    }

    float4 acc4[4];
#pragma unroll
    for (int p = 0; p < 4; ++p) acc4[p] = make_float4(0.f, 0.f, 0.f, 0.f);

#pragma unroll
    for (int kh = 0; kh < 7; ++kh) {
        const int hh = h + kh - 3;
        const float rm = ((unsigned)hh < 64u) ? 1.0f : 0.0f;
        const int hc = min(max(hh, 0), 63);
        const float* xr = xbase + ((size_t)hc << 14);
        float4 xv[10];
#pragma unroll
        for (int j = 0; j < 10; ++j) {
            xv[j] = *(const float4*)(xr + colc[j]);
            const float s = msk[j] * rm;
            xv[j].x *= s; xv[j].y *= s; xv[j].z *= s; xv[j].w *= s;
        }
#pragma unroll
        for (int p = 0; p < 4; ++p) {
            const float* kr = u.kl + (wv * 4 + p) * 784 + kh * 112 + g0;
#pragma unroll
            for (int kw = 0; kw < 7; ++kw) {
                const float4 kv = *(const float4*)(kr + kw * 16);
                FMA4(acc4[p], kv, xv[p + kw]);
            }
        }
    }
#pragma unroll
    for (int p = 0; p < 4; ++p)
        *(float4*)(out + (size_t)(pb + wv * 4 + p) * 256 + c0) = acc4[p];
}

extern "C" void kernel_launch(void* const* d_in, const int* in_sizes, int n_in,
                              void* d_out, int out_size, void* d_ws, size_t ws_size,
                              hipStream_t stream)
{
    const float* x      = (const float*)d_in[0];
    const float* w1     = (const float*)d_in[1];
    const float* b1     = (const float*)d_in[2];
    const float* gamma_ = (const float*)d_in[3];
    const float* beta_  = (const float*)d_in[4];
    const float* mu_    = (const float*)d_in[5];
    const float* var_   = (const float*)d_in[6];
    const float* w2     = (const float*)d_in[7];
    const float* b2     = (const float*)d_in[8];

    float* out  = (float*)d_out;
    float* kern = out + OUT_ELEMS;
    char*  base = (char*)d_ws;     // prepped weights in scratch; re-poisoned
                                   // each launch, prep rewrites them.

    prep<<<261, 256, 0, stream>>>(w1, w2, b1, gamma_, beta_, mu_, var_, base);
    invol_fused<<<512, 256, 0, stream>>>(x, base, b2, kern, out);
}